// Round 2
// baseline (972.918 us; speedup 1.0000x reference)
//
#include <hip/hip_runtime.h>
#include <hip/hip_bf16.h>
#include <math.h>

#define BATCH 2
#define SEQ   2048
#define EMB   2048
#define NH    16
#define HD    128

typedef __attribute__((ext_vector_type(8))) short short8;
typedef __attribute__((ext_vector_type(4))) float floatx4;

__device__ inline void async_load16(const void* g, void* l) {
    __builtin_amdgcn_global_load_lds(
        (const __attribute__((address_space(1))) unsigned int*)g,
        (__attribute__((address_space(3))) unsigned int*)l, 16, 0, 0);
}

__device__ inline unsigned short bf16_bits(float f) {
    __hip_bfloat16 b = __float2bfloat16(f);
    return *(unsigned short*)&b;
}
__device__ inline void split_bf16(float f, unsigned short& h, unsigned short& l) {
    __hip_bfloat16 hb = __float2bfloat16(f);
    h = *(unsigned short*)&hb;
    float r = f - __bfloat162float(hb);
    __hip_bfloat16 lb = __float2bfloat16(r);
    l = *(unsigned short*)&lb;
}

// ======================= plain bf16 MFMA GEMM (m97 structure) =======================
#define GT 128
#define GK 32

__global__ __launch_bounds__(256) void gemm_bf16(
    const unsigned short* __restrict__ A,
    const unsigned short* __restrict__ Bt,
    float* __restrict__ C, int M, int N, int K)
{
    __shared__ unsigned short As[GT * GK];
    __shared__ unsigned short Bs[GT * GK];

    const int tid  = threadIdx.x;
    const int w    = tid >> 6;
    const int lane = tid & 63;
    const int wr   = w >> 1, wc = w & 1;
    const int row0 = blockIdx.y * GT;
    const int col0 = blockIdx.x * GT;

    floatx4 acc[4][4];
    #pragma unroll
    for (int i = 0; i < 4; i++)
        #pragma unroll
        for (int j = 0; j < 4; j++)
            acc[i][j] = (floatx4){0.f, 0.f, 0.f, 0.f};

    const int srow  = lane >> 2;
    const int skoff = (lane & 3) * 8;
    const int fm = lane & 15;
    const int fk = (lane >> 4) * 8;

    for (int k0 = 0; k0 < K; k0 += GK) {
        #pragma unroll
        for (int t = 0; t < 2; t++) {
            const int c = w * 2 + t;
            async_load16(A  + (size_t)(row0 + c * 16 + srow) * K + k0 + skoff, (char*)As + c * 1024);
            async_load16(Bt + (size_t)(col0 + c * 16 + srow) * K + k0 + skoff, (char*)Bs + c * 1024);
        }
        __syncthreads();

        short8 af[4], bf[4];
        #pragma unroll
        for (int i = 0; i < 4; i++) {
            af[i] = *(const short8*)&As[(wr * 64 + i * 16 + fm) * GK + fk];
            bf[i] = *(const short8*)&Bs[(wc * 64 + i * 16 + fm) * GK + fk];
        }
        #pragma unroll
        for (int i = 0; i < 4; i++)
            #pragma unroll
            for (int j = 0; j < 4; j++)
                acc[i][j] = __builtin_amdgcn_mfma_f32_16x16x32_bf16(af[i], bf[j], acc[i][j], 0, 0, 0);
        __syncthreads();
    }

    const int quad = lane >> 4;
    #pragma unroll
    for (int i = 0; i < 4; i++)
        #pragma unroll
        for (int j = 0; j < 4; j++) {
            const size_t base = (size_t)(row0 + wr * 64 + i * 16 + quad * 4) * N
                              + col0 + wc * 64 + j * 16 + fm;
            #pragma unroll
            for (int r = 0; r < 4; r++)
                C[base + (size_t)r * N] = acc[i][j][r];
        }
}

// ======================= split (hi/lo) bf16 MFMA GEMM =======================
__global__ __launch_bounds__(256) void gemm_bf16_split(
    const unsigned short* __restrict__ Ah, const unsigned short* __restrict__ Al,
    const unsigned short* __restrict__ Bh, const unsigned short* __restrict__ Bl,
    float* __restrict__ C, int M, int N, int K)
{
    __shared__ unsigned short AsH[GT * GK], AsL[GT * GK];
    __shared__ unsigned short BsH[GT * GK], BsL[GT * GK];

    const int tid  = threadIdx.x;
    const int w    = tid >> 6;
    const int lane = tid & 63;
    const int wr   = w >> 1, wc = w & 1;
    const int row0 = blockIdx.y * GT;
    const int col0 = blockIdx.x * GT;

    floatx4 acc[4][4];
    #pragma unroll
    for (int i = 0; i < 4; i++)
        #pragma unroll
        for (int j = 0; j < 4; j++)
            acc[i][j] = (floatx4){0.f, 0.f, 0.f, 0.f};

    const int srow  = lane >> 2;
    const int skoff = (lane & 3) * 8;
    const int fm = lane & 15;
    const int fk = (lane >> 4) * 8;

    for (int k0 = 0; k0 < K; k0 += GK) {
        #pragma unroll
        for (int t = 0; t < 2; t++) {
            const int c = w * 2 + t;
            const size_t ao = (size_t)(row0 + c * 16 + srow) * K + k0 + skoff;
            const size_t bo = (size_t)(col0 + c * 16 + srow) * K + k0 + skoff;
            async_load16(Ah + ao, (char*)AsH + c * 1024);
            async_load16(Al + ao, (char*)AsL + c * 1024);
            async_load16(Bh + bo, (char*)BsH + c * 1024);
            async_load16(Bl + bo, (char*)BsL + c * 1024);
        }
        __syncthreads();

        short8 afh[4], afl[4], bfh[4], bfl[4];
        #pragma unroll
        for (int i = 0; i < 4; i++) {
            const int arow = (wr * 64 + i * 16 + fm) * GK + fk;
            const int brow = (wc * 64 + i * 16 + fm) * GK + fk;
            afh[i] = *(const short8*)&AsH[arow];
            afl[i] = *(const short8*)&AsL[arow];
            bfh[i] = *(const short8*)&BsH[brow];
            bfl[i] = *(const short8*)&BsL[brow];
        }
        #pragma unroll
        for (int i = 0; i < 4; i++)
            #pragma unroll
            for (int j = 0; j < 4; j++) {
                acc[i][j] = __builtin_amdgcn_mfma_f32_16x16x32_bf16(afh[i], bfh[j], acc[i][j], 0, 0, 0);
                acc[i][j] = __builtin_amdgcn_mfma_f32_16x16x32_bf16(afh[i], bfl[j], acc[i][j], 0, 0, 0);
                acc[i][j] = __builtin_amdgcn_mfma_f32_16x16x32_bf16(afl[i], bfh[j], acc[i][j], 0, 0, 0);
            }
        __syncthreads();
    }

    const int quad = lane >> 4;
    #pragma unroll
    for (int i = 0; i < 4; i++)
        #pragma unroll
        for (int j = 0; j < 4; j++) {
            const size_t base = (size_t)(row0 + wr * 64 + i * 16 + quad * 4) * N
                              + col0 + wc * 64 + j * 16 + fm;
            #pragma unroll
            for (int r = 0; r < 4; r++)
                C[base + (size_t)r * N] = acc[i][j][r];
        }
}

// ======================= casts / weight prep =======================
__global__ __launch_bounds__(256) void cast_split_f32(
    const float* __restrict__ in, unsigned short* __restrict__ hi,
    unsigned short* __restrict__ lo, int n)
{
    int i = (blockIdx.x * 256 + threadIdx.x) * 4;
    if (i >= n) return;
    float4 v = *(const float4*)&in[i];
    ushort4 h, l;
    split_bf16(v.x, h.x, l.x);
    split_bf16(v.y, h.y, l.y);
    split_bf16(v.z, h.z, l.z);
    split_bf16(v.w, h.w, l.w);
    *(ushort4*)&hi[i] = h;
    *(ushort4*)&lo[i] = l;
}

__global__ __launch_bounds__(256) void transpose_cast(
    const float* __restrict__ W, unsigned short* __restrict__ Wt, int K, int N)
{
    __shared__ float tile[32][33];
    const int k0 = blockIdx.y * 32, n0 = blockIdx.x * 32;
    const int tx = threadIdx.x, ty = threadIdx.y;
    #pragma unroll
    for (int i = 0; i < 4; i++)
        tile[ty + i * 8][tx] = W[(size_t)(k0 + ty + i * 8) * N + n0 + tx];
    __syncthreads();
    #pragma unroll
    for (int i = 0; i < 4; i++)
        Wt[(size_t)(n0 + ty + i * 8) * K + k0 + tx] = bf16_bits(tile[tx][ty + i * 8]);
}

__global__ __launch_bounds__(256) void transpose_cast_split(
    const float* __restrict__ W, unsigned short* __restrict__ WtH,
    unsigned short* __restrict__ WtL, int K, int N)
{
    __shared__ float tile[32][33];
    const int k0 = blockIdx.y * 32, n0 = blockIdx.x * 32;
    const int tx = threadIdx.x, ty = threadIdx.y;
    #pragma unroll
    for (int i = 0; i < 4; i++)
        tile[ty + i * 8][tx] = W[(size_t)(k0 + ty + i * 8) * N + n0 + tx];
    __syncthreads();
    #pragma unroll
    for (int i = 0; i < 4; i++) {
        unsigned short h, l;
        split_bf16(tile[tx][ty + i * 8], h, l);
        size_t idx = (size_t)(n0 + ty + i * 8) * K + k0 + tx;
        WtH[idx] = h;
        WtL[idx] = l;
    }
}

// ======================= prep_qk: rmsnorm + split + head-major relayout =======================
// reads from the fused QK GEMM output [M=4096, 4096] at column base `colbase`
__global__ __launch_bounds__(256) void prep_qk(
    const float* __restrict__ in, const float* __restrict__ scale,
    unsigned short* __restrict__ hi, unsigned short* __restrict__ lo,
    int swz, int colbase)
{
    __shared__ float ws4[4];
    const int r = blockIdx.x * 2 + (threadIdx.x >> 7);
    const int d = threadIdx.x & 127;
    const int b = r >> 15;
    const int s = (r >> 4) & 2047;
    const int h = r & 15;
    const float v = in[(size_t)(b * 2048 + s) * 4096 + colbase + h * 128 + d];
    float ss = v * v;
    #pragma unroll
    for (int off = 1; off < 64; off <<= 1) ss += __shfl_xor(ss, off, 64);
    if ((threadIdx.x & 63) == 0) ws4[threadIdx.x >> 6] = ss;
    __syncthreads();
    const int g = (threadIdx.x >> 7) << 1;
    const float inv = rsqrtf((ws4[g] + ws4[g + 1]) * (1.0f / HD) + 1e-6f);
    const float val = v * inv * scale[d];
    unsigned short hb, lb;
    split_bf16(val, hb, lb);
    const int dd = swz ? (((((d >> 3) ^ (s & 15))) << 3) | (d & 7)) : d;
    const size_t o = ((size_t)(b * NH + h) * SEQ + s) * 128 + dd;
    hi[o] = hb;
    lo[o] = lb;
}

// ======================= prep_v: V^T tiles of 64 keys, [d][key'] chunk-swizzled =======================
__global__ __launch_bounds__(256) void prep_v(
    const float* __restrict__ v, unsigned short* __restrict__ Vt)
{
    __shared__ unsigned short T[128][72];
    const int bh = blockIdx.y, ktile = blockIdx.x;
    const int b = bh >> 4, h = bh & 15;
    const int key = threadIdx.x >> 2, dg = threadIdx.x & 3;
    const size_t vrow = ((size_t)(b * SEQ + ktile * 64 + key) * NH + h) * 128;
    #pragma unroll
    for (int i2 = 0; i2 < 8; i2++) {
        const int d0 = dg * 4 + i2 * 16;
        float4 x = *(const float4*)&v[vrow + d0];
        T[d0 + 0][key] = bf16_bits(x.x);
        T[d0 + 1][key] = bf16_bits(x.y);
        T[d0 + 2][key] = bf16_bits(x.z);
        T[d0 + 3][key] = bf16_bits(x.w);
    }
    __syncthreads();
    const int d = threadIdx.x >> 1, half = threadIdx.x & 1;
    const size_t obase = ((size_t)bh * 32 + ktile) * 8192 + (size_t)d * 64;
    #pragma unroll
    for (int cc = 0; cc < 4; cc++) {
        const int cs = half * 4 + cc;
        const int kb = (cs ^ (d & 7)) << 3;
        short8 val = *(const short8*)&T[d][kb];
        *(short8*)&Vt[obase + cs * 8] = val;
    }
}

// ======================= MFMA flash attention v6 =======================
// ATQ=128 (16 q-rows/wave), ATK=64, 8 waves.
// Single-buffered K and V (2 barriers/tile): LDS = 16+16+16+16 = 64 KB -> 2 blocks/CU.
// Grid 512 blocks -> 4 waves/SIMD (occupancy ~50%).
// XCD-bijective work swizzle: all 16 q-blocks of a head on one XCD (K/V L2 locality).
// v4's conflict-free 8/16-chunk XOR layouts throughout.
#define ATQ 128
#define ATK 64
#define NT  (SEQ / ATK)

__global__ __launch_bounds__(512, 4) void attn6(
    const unsigned short* __restrict__ Qh, const unsigned short* __restrict__ Ql,
    const unsigned short* __restrict__ Kh, const unsigned short* __restrict__ Kl,
    const unsigned short* __restrict__ Vt, __hip_bfloat16* __restrict__ AO)
{
    __shared__ unsigned short KsH[ATK * 128];   // 16 KB  [key][d'] (chunk ^= key&15)
    __shared__ unsigned short KsL[ATK * 128];   // 16 KB
    __shared__ unsigned short Vts[HD * ATK];    // 16 KB  [d][key'] (chunk ^= d&7)
    __shared__ unsigned short Ps[ATQ * ATK];    // 16 KB  P[row][key'] (chunk ^= row&7)

    const int tid  = threadIdx.x;
    const int w    = tid >> 6;        // 0..7
    const int lane = tid & 63;
    const int quad = lane >> 4;
    const int fm   = lane & 15;

    // XCD-aware work assignment: hardware XCD = dispatch_linear % 8.
    // Give XCD x heads x*4..x*4+3; all 16 q-blocks of a head share one XCD's L2.
    const int L   = blockIdx.y * 16 + blockIdx.x;    // 0..511
    const int xcd = L & 7;
    const int g   = L >> 3;                          // 0..63
    const int bh  = xcd * 4 + (g & 3);
    const int q0  = (g >> 2) * ATQ;
    const int b = bh >> 4, h = bh & 15;

    const size_t hbase = (size_t)(b * NH + h) * SEQ;

    // ---- Q fragments (pre-split bf16); wave owns rows w*16..w*16+15 ----
    short8 qh[4], ql[4];
    {
        const size_t row = hbase + q0 + w * 16 + fm;
        #pragma unroll
        for (int kc = 0; kc < 4; kc++) {
            const size_t off = row * 128 + kc * 32 + quad * 8;
            qh[kc] = *(const short8*)&Qh[off];
            ql[kc] = *(const short8*)&Ql[off];
        }
    }

    floatx4 oacc[8];
    #pragma unroll
    for (int df = 0; df < 8; df++)
        oacc[df] = (floatx4){0.f, 0.f, 0.f, 0.f};
    float m_[4], l_[4];
    #pragma unroll
    for (int r = 0; r < 4; r++) { m_[r] = -1e30f; l_[r] = 0.f; }

    const unsigned short* gkh0 = Kh + hbase * 128;
    const unsigned short* gkl0 = Kl + hbase * 128;
    const unsigned short* gvt0 = Vt + (size_t)bh * SEQ * 128;

    // K staging: 32 chunks of 1 KB (KsH 16, KsL 16); wave w -> chunks w*4..w*4+3
    // V staging: 16 chunks of 1 KB; wave w -> chunks w*2..w*2+1
    // ---- prologue: stage tile 0 ----
    #pragma unroll
    for (int c = 0; c < 4; c++) {
        const int ch = w * 4 + c;
        const size_t go = (size_t)(ch & 15) * 512 + lane * 8;
        if (ch < 16) async_load16(gkh0 + go, (char*)KsH + (ch & 15) * 1024);
        else         async_load16(gkl0 + go, (char*)KsL + (ch & 15) * 1024);
    }
    #pragma unroll
    for (int c = 0; c < 2; c++) {
        const int cv = w * 2 + c;
        const size_t go = (size_t)cv * 512 + lane * 8;
        async_load16(gvt0 + go, (char*)Vts + cv * 1024);
    }
    __syncthreads();   // drain: tile 0 staged

    for (int ktile = 0; ktile < NT; ktile++) {
        // ---- S = Q K^T (3-term hi/lo) ----
        floatx4 sacc[4];
        #pragma unroll
        for (int jf = 0; jf < 4; jf++)
            sacc[jf] = (floatx4){0.f, 0.f, 0.f, 0.f};
        __builtin_amdgcn_s_setprio(1);
        #pragma unroll
        for (int kc = 0; kc < 4; kc++)
            #pragma unroll
            for (int jf = 0; jf < 4; jf++) {
                const int koff = (jf * 16 + fm) * 128 + (((kc * 4 + quad) ^ fm) << 3);
                short8 kh8 = *(const short8*)&KsH[koff];
                short8 kl8 = *(const short8*)&KsL[koff];
                sacc[jf] = __builtin_amdgcn_mfma_f32_16x16x32_bf16(qh[kc], kh8, sacc[jf], 0, 0, 0);
                sacc[jf] = __builtin_amdgcn_mfma_f32_16x16x32_bf16(qh[kc], kl8, sacc[jf], 0, 0, 0);
                sacc[jf] = __builtin_amdgcn_mfma_f32_16x16x32_bf16(ql[kc], kh8, sacc[jf], 0, 0, 0);
            }
        __builtin_amdgcn_s_setprio(0);

        __syncthreads();   // barrier 1: all waves done reading Ks (drains last V-prefetch too)

        // ---- issue K prefetch (t+1) into the SAME buffers (safe after barrier 1) ----
        if (ktile + 1 < NT) {
            const unsigned short* gkh = gkh0 + (size_t)(ktile + 1) * ATK * 128;
            const unsigned short* gkl = gkl0 + (size_t)(ktile + 1) * ATK * 128;
            #pragma unroll
            for (int c = 0; c < 4; c++) {
                const int ch = w * 4 + c;
                const size_t go = (size_t)(ch & 15) * 512 + lane * 8;
                if (ch < 16) async_load16(gkh + go, (char*)KsH + (ch & 15) * 1024);
                else         async_load16(gkl + go, (char*)KsL + (ch & 15) * 1024);
            }
        }

        // ---- online softmax (registers) with defer-max (THR=8) ----
        #pragma unroll
        for (int r = 0; r < 4; r++) {
            float mx = fmaxf(fmaxf(sacc[0][r], sacc[1][r]),
                             fmaxf(sacc[2][r], sacc[3][r]));
            mx = fmaxf(mx, __shfl_xor(mx, 1, 64));
            mx = fmaxf(mx, __shfl_xor(mx, 2, 64));
            mx = fmaxf(mx, __shfl_xor(mx, 4, 64));
            mx = fmaxf(mx, __shfl_xor(mx, 8, 64));
            const float mold = m_[r];
            if (__all(mx <= mold + 8.0f)) {
                float rs = 0.f;
                #pragma unroll
                for (int jf = 0; jf < 4; jf++) {
                    float p = __expf(sacc[jf][r] - mold);
                    sacc[jf][r] = p;
                    rs += p;
                }
                rs += __shfl_xor(rs, 1, 64);
                rs += __shfl_xor(rs, 2, 64);
                rs += __shfl_xor(rs, 4, 64);
                rs += __shfl_xor(rs, 8, 64);
                l_[r] += rs;
            } else {
                const float mnew = fmaxf(mold, mx);
                const float al = __expf(mold - mnew);
                m_[r] = mnew;
                float rs = 0.f;
                #pragma unroll
                for (int jf = 0; jf < 4; jf++) {
                    float p = __expf(sacc[jf][r] - mnew);
                    sacc[jf][r] = p;
                    rs += p;
                }
                rs += __shfl_xor(rs, 1, 64);
                rs += __shfl_xor(rs, 2, 64);
                rs += __shfl_xor(rs, 4, 64);
                rs += __shfl_xor(rs, 8, 64);
                l_[r] = l_[r] * al + rs;
                #pragma unroll
                for (int df = 0; df < 8; df++)
                    oacc[df][r] *= al;
            }
        }

        // ---- P -> bf16 into Ps (own rows; wave-local ordering, no barrier) ----
        #pragma unroll
        for (int jf = 0; jf < 4; jf++)
            #pragma unroll
            for (int r = 0; r < 4; r++) {
                const int row = w * 16 + quad * 4 + r;
                const int chunk = jf * 2 + (fm >> 3);
                const int colp = ((chunk ^ (row & 7)) << 3) | (fm & 7);
                Ps[row * 64 + colp] = bf16_bits(sacc[jf][r]);
            }

        // ---- O += P V ----
        __builtin_amdgcn_s_setprio(1);
        #pragma unroll
        for (int kc2 = 0; kc2 < 2; kc2++) {
            short8 ap;
            {
                const int row = w * 16 + fm;
                ap = *(const short8*)&Ps[row * 64 + (((kc2 * 4 + quad) ^ (row & 7)) << 3)];
            }
            #pragma unroll
            for (int df = 0; df < 8; df++) {
                const int d = df * 16 + fm;
                short8 bv = *(const short8*)&Vts[d * 64 + (((kc2 * 4 + quad) ^ (d & 7)) << 3)];
                oacc[df] = __builtin_amdgcn_mfma_f32_16x16x32_bf16(ap, bv, oacc[df], 0, 0, 0);
            }
        }
        __builtin_amdgcn_s_setprio(0);

        __syncthreads();   // barrier 2: all waves done reading Vts; drains K-prefetch

        // ---- issue V prefetch (t+1) (safe after barrier 2; drained at next barrier 1) ----
        if (ktile + 1 < NT) {
            const unsigned short* gvt = gvt0 + (size_t)(ktile + 1) * ATK * 128;
            #pragma unroll
            for (int c = 0; c < 2; c++) {
                const int cv = w * 2 + c;
                const size_t go = (size_t)cv * 512 + lane * 8;
                async_load16(gvt + go, (char*)Vts + cv * 1024);
            }
        }
    }

    // ---- epilogue: AO bf16 [b,s,h,d] ----
    const size_t obase = ((size_t)b * SEQ * NH + h) * HD;
    const size_t rstr = (size_t)NH * HD;
    float linv[4];
    #pragma unroll
    for (int r = 0; r < 4; r++) linv[r] = 1.0f / l_[r];
    #pragma unroll
    for (int df = 0; df < 8; df++)
        #pragma unroll
        for (int r = 0; r < 4; r++) {
            const int row = q0 + w * 16 + quad * 4 + r;
            const int d = df * 16 + fm;
            AO[obase + (size_t)row * rstr + d] = __float2bfloat16(oacc[df][r] * linv[r]);
        }
}

// ======================= launch =======================
extern "C" void kernel_launch(void* const* d_in, const int* in_sizes, int n_in,
                              void* d_out, int out_size, void* d_ws, size_t ws_size,
                              hipStream_t stream) {
    const float* x  = (const float*)d_in[0];
    const float* wq = (const float*)d_in[1];
    const float* wk = (const float*)d_in[2];
    const float* wv = (const float*)d_in[3];
    const float* wo = (const float*)d_in[4];
    const float* q_scale = (const float*)d_in[5];
    const float* k_scale = (const float*)d_in[6];
    float* out = (float*)d_out;

    const size_t T = (size_t)BATCH * SEQ * NH * HD;   // 8388608
    const size_t W = (size_t)EMB * NH * HD;           // 4194304

    const int M = BATCH * SEQ;   // 4096
    const int N = NH * HD;       // 2048
    const int K = EMB;           // 2048

    float* qk = (float*)d_ws;                         // fp32 fused QK output [M, 4096]
    float* v  = qk + (size_t)M * 4096;                // fp32 [b,s,h,d]
    unsigned short* xh   = (unsigned short*)(v + T);  // reused as Qh after GEMMs
    unsigned short* xl   = xh + T;                    // reused as Ql
    unsigned short* aob  = xl + T;
    unsigned short* Kh   = aob + T;
    unsigned short* Kl   = Kh + T;
    unsigned short* Vtb  = Kl + T;
    unsigned short* wqkTh = Vtb + T;                  // [2W] wq then wk, [n][k]
    unsigned short* wqkTl = wqkTh + 2 * W;            // [2W]
    unsigned short* wvT  = wqkTl + 2 * W;
    unsigned short* woT  = wvT + W;

    cast_split_f32<<<(int)(T / 4 + 255) / 256, 256, 0, stream>>>(x, xh, xl, (int)T);
    dim3 tblk(32, 8);
    transpose_cast_split<<<dim3(N / 32, K / 32), tblk, 0, stream>>>(wq, wqkTh, wqkTl, K, N);
    transpose_cast_split<<<dim3(N / 32, K / 32), tblk, 0, stream>>>(wk, wqkTh + W, wqkTl + W, K, N);
    transpose_cast<<<dim3(N / 32, K / 32), tblk, 0, stream>>>(wv, wvT, K, N);
    transpose_cast<<<dim3(EMB / 32, (NH * HD) / 32), tblk, 0, stream>>>(wo, woT, NH * HD, EMB);

    // fused Q+K split projection: [M,K] x [K,4096] -> [M,4096]
    gemm_bf16_split<<<dim3(2 * N / GT, M / GT), 256, 0, stream>>>(xh, xl, wqkTh, wqkTl, qk, M, 2 * N, K);
    gemm_bf16<<<dim3(N / GT, M / GT), 256, 0, stream>>>(xh, wvT, v, M, N, K);

    unsigned short* Qh = xh;
    unsigned short* Ql = xl;
    prep_qk<<<(int)(T / 128 / 2), 256, 0, stream>>>(qk, q_scale, Qh, Ql, 0, 0);
    prep_qk<<<(int)(T / 128 / 2), 256, 0, stream>>>(qk, k_scale, Kh, Kl, 1, 2048);
    prep_v<<<dim3(SEQ / ATK, BATCH * NH), 256, 0, stream>>>(v, Vtb);

    attn6<<<dim3(16, BATCH * NH), 512, 0, stream>>>(Qh, Ql, Kh, Kl, Vtb, (__hip_bfloat16*)aob);

    gemm_bf16<<<dim3(EMB / GT, M / GT), 256, 0, stream>>>(aob, woT, out, M, EMB, NH * HD);
}

// Round 3
// 928.091 us; speedup vs baseline: 1.0483x; 1.0483x over previous
//
#include <hip/hip_runtime.h>
#include <hip/hip_bf16.h>
#include <math.h>

#define BATCH 2
#define SEQ   2048
#define EMB   2048
#define NH    16
#define HD    128

typedef __attribute__((ext_vector_type(8))) short short8;
typedef __attribute__((ext_vector_type(4))) float floatx4;

__device__ inline void async_load16(const void* g, void* l) {
    __builtin_amdgcn_global_load_lds(
        (const __attribute__((address_space(1))) unsigned int*)g,
        (__attribute__((address_space(3))) unsigned int*)l, 16, 0, 0);
}

__device__ inline unsigned short bf16_bits(float f) {
    __hip_bfloat16 b = __float2bfloat16(f);
    return *(unsigned short*)&b;
}
__device__ inline void split_bf16(float f, unsigned short& h, unsigned short& l) {
    __hip_bfloat16 hb = __float2bfloat16(f);
    h = *(unsigned short*)&hb;
    float r = f - __bfloat162float(hb);
    __hip_bfloat16 lb = __float2bfloat16(r);
    l = *(unsigned short*)&lb;
}

// ======================= plain bf16 MFMA GEMM (m97 structure) =======================
#define GT 128
#define GK 32

__global__ __launch_bounds__(256) void gemm_bf16(
    const unsigned short* __restrict__ A,
    const unsigned short* __restrict__ Bt,
    float* __restrict__ C, int M, int N, int K)
{
    __shared__ unsigned short As[GT * GK];
    __shared__ unsigned short Bs[GT * GK];

    const int tid  = threadIdx.x;
    const int w    = tid >> 6;
    const int lane = tid & 63;
    const int wr   = w >> 1, wc = w & 1;
    const int row0 = blockIdx.y * GT;
    const int col0 = blockIdx.x * GT;

    floatx4 acc[4][4];
    #pragma unroll
    for (int i = 0; i < 4; i++)
        #pragma unroll
        for (int j = 0; j < 4; j++)
            acc[i][j] = (floatx4){0.f, 0.f, 0.f, 0.f};

    const int srow  = lane >> 2;
    const int skoff = (lane & 3) * 8;
    const int fm = lane & 15;
    const int fk = (lane >> 4) * 8;

    for (int k0 = 0; k0 < K; k0 += GK) {
        #pragma unroll
        for (int t = 0; t < 2; t++) {
            const int c = w * 2 + t;
            async_load16(A  + (size_t)(row0 + c * 16 + srow) * K + k0 + skoff, (char*)As + c * 1024);
            async_load16(Bt + (size_t)(col0 + c * 16 + srow) * K + k0 + skoff, (char*)Bs + c * 1024);
        }
        __syncthreads();

        short8 af[4], bf[4];
        #pragma unroll
        for (int i = 0; i < 4; i++) {
            af[i] = *(const short8*)&As[(wr * 64 + i * 16 + fm) * GK + fk];
            bf[i] = *(const short8*)&Bs[(wc * 64 + i * 16 + fm) * GK + fk];
        }
        #pragma unroll
        for (int i = 0; i < 4; i++)
            #pragma unroll
            for (int j = 0; j < 4; j++)
                acc[i][j] = __builtin_amdgcn_mfma_f32_16x16x32_bf16(af[i], bf[j], acc[i][j], 0, 0, 0);
        __syncthreads();
    }

    const int quad = lane >> 4;
    #pragma unroll
    for (int i = 0; i < 4; i++)
        #pragma unroll
        for (int j = 0; j < 4; j++) {
            const size_t base = (size_t)(row0 + wr * 64 + i * 16 + quad * 4) * N
                              + col0 + wc * 64 + j * 16 + fm;
            #pragma unroll
            for (int r = 0; r < 4; r++)
                C[base + (size_t)r * N] = acc[i][j][r];
        }
}

// ======================= split (hi/lo) bf16 MFMA GEMM =======================
__global__ __launch_bounds__(256) void gemm_bf16_split(
    const unsigned short* __restrict__ Ah, const unsigned short* __restrict__ Al,
    const unsigned short* __restrict__ Bh, const unsigned short* __restrict__ Bl,
    float* __restrict__ C, int M, int N, int K)
{
    __shared__ unsigned short AsH[GT * GK], AsL[GT * GK];
    __shared__ unsigned short BsH[GT * GK], BsL[GT * GK];

    const int tid  = threadIdx.x;
    const int w    = tid >> 6;
    const int lane = tid & 63;
    const int wr   = w >> 1, wc = w & 1;
    const int row0 = blockIdx.y * GT;
    const int col0 = blockIdx.x * GT;

    floatx4 acc[4][4];
    #pragma unroll
    for (int i = 0; i < 4; i++)
        #pragma unroll
        for (int j = 0; j < 4; j++)
            acc[i][j] = (floatx4){0.f, 0.f, 0.f, 0.f};

    const int srow  = lane >> 2;
    const int skoff = (lane & 3) * 8;
    const int fm = lane & 15;
    const int fk = (lane >> 4) * 8;

    for (int k0 = 0; k0 < K; k0 += GK) {
        #pragma unroll
        for (int t = 0; t < 2; t++) {
            const int c = w * 2 + t;
            const size_t ao = (size_t)(row0 + c * 16 + srow) * K + k0 + skoff;
            const size_t bo = (size_t)(col0 + c * 16 + srow) * K + k0 + skoff;
            async_load16(Ah + ao, (char*)AsH + c * 1024);
            async_load16(Al + ao, (char*)AsL + c * 1024);
            async_load16(Bh + bo, (char*)BsH + c * 1024);
            async_load16(Bl + bo, (char*)BsL + c * 1024);
        }
        __syncthreads();

        short8 afh[4], afl[4], bfh[4], bfl[4];
        #pragma unroll
        for (int i = 0; i < 4; i++) {
            const int arow = (wr * 64 + i * 16 + fm) * GK + fk;
            const int brow = (wc * 64 + i * 16 + fm) * GK + fk;
            afh[i] = *(const short8*)&AsH[arow];
            afl[i] = *(const short8*)&AsL[arow];
            bfh[i] = *(const short8*)&BsH[brow];
            bfl[i] = *(const short8*)&BsL[brow];
        }
        #pragma unroll
        for (int i = 0; i < 4; i++)
            #pragma unroll
            for (int j = 0; j < 4; j++) {
                acc[i][j] = __builtin_amdgcn_mfma_f32_16x16x32_bf16(afh[i], bfh[j], acc[i][j], 0, 0, 0);
                acc[i][j] = __builtin_amdgcn_mfma_f32_16x16x32_bf16(afh[i], bfl[j], acc[i][j], 0, 0, 0);
                acc[i][j] = __builtin_amdgcn_mfma_f32_16x16x32_bf16(afl[i], bfh[j], acc[i][j], 0, 0, 0);
            }
        __syncthreads();
    }

    const int quad = lane >> 4;
    #pragma unroll
    for (int i = 0; i < 4; i++)
        #pragma unroll
        for (int j = 0; j < 4; j++) {
            const size_t base = (size_t)(row0 + wr * 64 + i * 16 + quad * 4) * N
                              + col0 + wc * 64 + j * 16 + fm;
            #pragma unroll
            for (int r = 0; r < 4; r++)
                C[base + (size_t)r * N] = acc[i][j][r];
        }
}

// ======================= casts / weight prep =======================
__global__ __launch_bounds__(256) void cast_split_f32(
    const float* __restrict__ in, unsigned short* __restrict__ hi,
    unsigned short* __restrict__ lo, int n)
{
    int i = (blockIdx.x * 256 + threadIdx.x) * 4;
    if (i >= n) return;
    float4 v = *(const float4*)&in[i];
    ushort4 h, l;
    split_bf16(v.x, h.x, l.x);
    split_bf16(v.y, h.y, l.y);
    split_bf16(v.z, h.z, l.z);
    split_bf16(v.w, h.w, l.w);
    *(ushort4*)&hi[i] = h;
    *(ushort4*)&lo[i] = l;
}

__global__ __launch_bounds__(256) void transpose_cast(
    const float* __restrict__ W, unsigned short* __restrict__ Wt, int K, int N)
{
    __shared__ float tile[32][33];
    const int k0 = blockIdx.y * 32, n0 = blockIdx.x * 32;
    const int tx = threadIdx.x, ty = threadIdx.y;
    #pragma unroll
    for (int i = 0; i < 4; i++)
        tile[ty + i * 8][tx] = W[(size_t)(k0 + ty + i * 8) * N + n0 + tx];
    __syncthreads();
    #pragma unroll
    for (int i = 0; i < 4; i++)
        Wt[(size_t)(n0 + ty + i * 8) * K + k0 + tx] = bf16_bits(tile[tx][ty + i * 8]);
}

__global__ __launch_bounds__(256) void transpose_cast_split(
    const float* __restrict__ W, unsigned short* __restrict__ WtH,
    unsigned short* __restrict__ WtL, int K, int N)
{
    __shared__ float tile[32][33];
    const int k0 = blockIdx.y * 32, n0 = blockIdx.x * 32;
    const int tx = threadIdx.x, ty = threadIdx.y;
    #pragma unroll
    for (int i = 0; i < 4; i++)
        tile[ty + i * 8][tx] = W[(size_t)(k0 + ty + i * 8) * N + n0 + tx];
    __syncthreads();
    #pragma unroll
    for (int i = 0; i < 4; i++) {
        unsigned short h, l;
        split_bf16(tile[tx][ty + i * 8], h, l);
        size_t idx = (size_t)(n0 + ty + i * 8) * K + k0 + tx;
        WtH[idx] = h;
        WtL[idx] = l;
    }
}

// ======================= prep_qk: rmsnorm + split + head-major relayout =======================
__global__ __launch_bounds__(256) void prep_qk(
    const float* __restrict__ in, const float* __restrict__ scale,
    unsigned short* __restrict__ hi, unsigned short* __restrict__ lo, int swz)
{
    __shared__ float ws4[4];
    const int r = blockIdx.x * 2 + (threadIdx.x >> 7);
    const int d = threadIdx.x & 127;
    const int b = r >> 15;
    const int s = (r >> 4) & 2047;
    const int h = r & 15;
    const float v = in[(size_t)r * 128 + d];
    float ss = v * v;
    #pragma unroll
    for (int off = 1; off < 64; off <<= 1) ss += __shfl_xor(ss, off, 64);
    if ((threadIdx.x & 63) == 0) ws4[threadIdx.x >> 6] = ss;
    __syncthreads();
    const int g = (threadIdx.x >> 7) << 1;
    const float inv = rsqrtf((ws4[g] + ws4[g + 1]) * (1.0f / HD) + 1e-6f);
    const float val = v * inv * scale[d];
    unsigned short hb, lb;
    split_bf16(val, hb, lb);
    const int dd = swz ? (((((d >> 3) ^ (s & 15))) << 3) | (d & 7)) : d;
    const size_t o = ((size_t)(b * NH + h) * SEQ + s) * 128 + dd;
    hi[o] = hb;
    lo[o] = lb;
}

// ======================= prep_v: V^T tiles of 64 keys, [d][key'] chunk-swizzled =======================
__global__ __launch_bounds__(256) void prep_v(
    const float* __restrict__ v, unsigned short* __restrict__ Vt)
{
    __shared__ unsigned short T[128][72];
    const int bh = blockIdx.y, ktile = blockIdx.x;
    const int b = bh >> 4, h = bh & 15;
    const int key = threadIdx.x >> 2, dg = threadIdx.x & 3;
    const size_t vrow = ((size_t)(b * SEQ + ktile * 64 + key) * NH + h) * 128;
    #pragma unroll
    for (int i2 = 0; i2 < 8; i2++) {
        const int d0 = dg * 4 + i2 * 16;
        float4 x = *(const float4*)&v[vrow + d0];
        T[d0 + 0][key] = bf16_bits(x.x);
        T[d0 + 1][key] = bf16_bits(x.y);
        T[d0 + 2][key] = bf16_bits(x.z);
        T[d0 + 3][key] = bf16_bits(x.w);
    }
    __syncthreads();
    const int d = threadIdx.x >> 1, half = threadIdx.x & 1;
    const size_t obase = ((size_t)bh * 32 + ktile) * 8192 + (size_t)d * 64;
    #pragma unroll
    for (int cc = 0; cc < 4; cc++) {
        const int cs = half * 4 + cc;
        const int kb = (cs ^ (d & 7)) << 3;
        short8 val = *(const short8*)&T[d][kb];
        *(short8*)&Vt[obase + cs * 8] = val;
    }
}

// ======================= MFMA flash attention v7 =======================
// ATQ=256, ATK=64: v4's memory footprint (8 q-blocks/head, fetch ~217 MB) but
// 1024 threads = 16 waves (16 q-rows each) -> 4 waves/SIMD (2x v4 occupancy).
// Single-buffered K/V/Ps: LDS = 16+16+16+32 = 80 KB, 1 block/CU.
// 2 barriers/tile; prefetch into same buffer issued right after the barrier
// that retires its reader. 3x 1KB global_load_lds per wave per tile.
#define ATQ 256
#define ATK 64
#define NT  (SEQ / ATK)

__global__ __launch_bounds__(1024, 4) void attn7(
    const unsigned short* __restrict__ Qh, const unsigned short* __restrict__ Ql,
    const unsigned short* __restrict__ Kh, const unsigned short* __restrict__ Kl,
    const unsigned short* __restrict__ Vt, __hip_bfloat16* __restrict__ AO)
{
    __shared__ unsigned short KsH[ATK * 128];   // 16 KB  [key][d'] (chunk ^= key&15)
    __shared__ unsigned short KsL[ATK * 128];   // 16 KB
    __shared__ unsigned short Vts[HD * ATK];    // 16 KB  [d][key'] (chunk ^= d&7)
    __shared__ unsigned short Ps[ATQ * ATK];    // 32 KB  P[row][key'] (chunk ^= row&7)

    const int tid  = threadIdx.x;
    const int w    = tid >> 6;        // 0..15
    const int lane = tid & 63;
    const int quad = lane >> 4;
    const int fm   = lane & 15;
    const int bh = blockIdx.y;
    const int b = bh >> 4, h = bh & 15;
    const int q0 = blockIdx.x * ATQ;

    const size_t hbase = (size_t)(b * NH + h) * SEQ;

    // ---- Q fragments (pre-split bf16); wave owns rows w*16..w*16+15 ----
    short8 qh[4], ql[4];
    {
        const size_t row = hbase + q0 + w * 16 + fm;
        #pragma unroll
        for (int kc = 0; kc < 4; kc++) {
            const size_t off = row * 128 + kc * 32 + quad * 8;
            qh[kc] = *(const short8*)&Qh[off];
            ql[kc] = *(const short8*)&Ql[off];
        }
    }

    floatx4 oacc[8];
    #pragma unroll
    for (int df = 0; df < 8; df++)
        oacc[df] = (floatx4){0.f, 0.f, 0.f, 0.f};
    float m_[4], l_[4];
    #pragma unroll
    for (int r = 0; r < 4; r++) { m_[r] = -1e30f; l_[r] = 0.f; }

    const unsigned short* gkh0 = Kh + hbase * 128;
    const unsigned short* gkl0 = Kl + hbase * 128;
    const unsigned short* gvt0 = Vt + (size_t)bh * SEQ * 128;

    // staging: each of KsH/KsL/Vts is 16 chunks of 1 KB; wave w owns chunk w in each.
    const size_t sgo = (size_t)w * 512 + lane * 8;

    // ---- prologue: stage tile 0 ----
    async_load16(gkh0 + sgo, (char*)KsH + w * 1024);
    async_load16(gkl0 + sgo, (char*)KsL + w * 1024);
    async_load16(gvt0 + sgo, (char*)Vts + w * 1024);
    __syncthreads();   // drain: tile 0 staged

    for (int ktile = 0; ktile < NT; ktile++) {
        // ---- S = Q K^T (3-term hi/lo) ----
        floatx4 sacc[4];
        #pragma unroll
        for (int jf = 0; jf < 4; jf++)
            sacc[jf] = (floatx4){0.f, 0.f, 0.f, 0.f};
        __builtin_amdgcn_s_setprio(1);
        #pragma unroll
        for (int kc = 0; kc < 4; kc++)
            #pragma unroll
            for (int jf = 0; jf < 4; jf++) {
                const int koff = (jf * 16 + fm) * 128 + (((kc * 4 + quad) ^ fm) << 3);
                short8 kh8 = *(const short8*)&KsH[koff];
                short8 kl8 = *(const short8*)&KsL[koff];
                sacc[jf] = __builtin_amdgcn_mfma_f32_16x16x32_bf16(qh[kc], kh8, sacc[jf], 0, 0, 0);
                sacc[jf] = __builtin_amdgcn_mfma_f32_16x16x32_bf16(qh[kc], kl8, sacc[jf], 0, 0, 0);
                sacc[jf] = __builtin_amdgcn_mfma_f32_16x16x32_bf16(ql[kc], kh8, sacc[jf], 0, 0, 0);
            }
        __builtin_amdgcn_s_setprio(0);

        __syncthreads();   // barrier 1: all waves done reading Ks; drains V prefetch

        // ---- issue K prefetch (t+1) into same buffers (safe after barrier 1) ----
        if (ktile + 1 < NT) {
            const unsigned short* gkh = gkh0 + (size_t)(ktile + 1) * ATK * 128;
            const unsigned short* gkl = gkl0 + (size_t)(ktile + 1) * ATK * 128;
            async_load16(gkh + sgo, (char*)KsH + w * 1024);
            async_load16(gkl + sgo, (char*)KsL + w * 1024);
        }

        // ---- online softmax (registers) with defer-max (THR=8) ----
        #pragma unroll
        for (int r = 0; r < 4; r++) {
            float mx = fmaxf(fmaxf(sacc[0][r], sacc[1][r]),
                             fmaxf(sacc[2][r], sacc[3][r]));
            mx = fmaxf(mx, __shfl_xor(mx, 1, 64));
            mx = fmaxf(mx, __shfl_xor(mx, 2, 64));
            mx = fmaxf(mx, __shfl_xor(mx, 4, 64));
            mx = fmaxf(mx, __shfl_xor(mx, 8, 64));
            const float mold = m_[r];
            if (__all(mx <= mold + 8.0f)) {
                float rs = 0.f;
                #pragma unroll
                for (int jf = 0; jf < 4; jf++) {
                    float p = __expf(sacc[jf][r] - mold);
                    sacc[jf][r] = p;
                    rs += p;
                }
                rs += __shfl_xor(rs, 1, 64);
                rs += __shfl_xor(rs, 2, 64);
                rs += __shfl_xor(rs, 4, 64);
                rs += __shfl_xor(rs, 8, 64);
                l_[r] += rs;
            } else {
                const float mnew = fmaxf(mold, mx);
                const float al = __expf(mold - mnew);
                m_[r] = mnew;
                float rs = 0.f;
                #pragma unroll
                for (int jf = 0; jf < 4; jf++) {
                    float p = __expf(sacc[jf][r] - mnew);
                    sacc[jf][r] = p;
                    rs += p;
                }
                rs += __shfl_xor(rs, 1, 64);
                rs += __shfl_xor(rs, 2, 64);
                rs += __shfl_xor(rs, 4, 64);
                rs += __shfl_xor(rs, 8, 64);
                l_[r] = l_[r] * al + rs;
                #pragma unroll
                for (int df = 0; df < 8; df++)
                    oacc[df][r] *= al;
            }
        }

        // ---- P -> bf16 into Ps (own rows; wave-local ordering, no barrier) ----
        #pragma unroll
        for (int jf = 0; jf < 4; jf++)
            #pragma unroll
            for (int r = 0; r < 4; r++) {
                const int row = w * 16 + quad * 4 + r;
                const int chunk = jf * 2 + (fm >> 3);
                const int colp = ((chunk ^ (row & 7)) << 3) | (fm & 7);
                Ps[row * 64 + colp] = bf16_bits(sacc[jf][r]);
            }

        // ---- O += P V ----
        __builtin_amdgcn_s_setprio(1);
        #pragma unroll
        for (int kc2 = 0; kc2 < 2; kc2++) {
            short8 ap;
            {
                const int row = w * 16 + fm;
                ap = *(const short8*)&Ps[row * 64 + (((kc2 * 4 + quad) ^ (row & 7)) << 3)];
            }
            #pragma unroll
            for (int df = 0; df < 8; df++) {
                const int d = df * 16 + fm;
                short8 bv = *(const short8*)&Vts[d * 64 + (((kc2 * 4 + quad) ^ (d & 7)) << 3)];
                oacc[df] = __builtin_amdgcn_mfma_f32_16x16x32_bf16(ap, bv, oacc[df], 0, 0, 0);
            }
        }
        __builtin_amdgcn_s_setprio(0);

        __syncthreads();   // barrier 2: all waves done reading Vts; drains K prefetch

        // ---- issue V prefetch (t+1) (drained at next barrier 1) ----
        if (ktile + 1 < NT) {
            const unsigned short* gvt = gvt0 + (size_t)(ktile + 1) * ATK * 128;
            async_load16(gvt + sgo, (char*)Vts + w * 1024);
        }
    }

    // ---- epilogue: AO bf16 [b,s,h,d] ----
    const size_t obase = ((size_t)b * SEQ * NH + h) * HD;
    const size_t rstr = (size_t)NH * HD;
    float linv[4];
    #pragma unroll
    for (int r = 0; r < 4; r++) linv[r] = 1.0f / l_[r];
    #pragma unroll
    for (int df = 0; df < 8; df++)
        #pragma unroll
        for (int r = 0; r < 4; r++) {
            const int row = q0 + w * 16 + quad * 4 + r;
            const int d = df * 16 + fm;
            AO[obase + (size_t)row * rstr + d] = __float2bfloat16(oacc[df][r] * linv[r]);
        }
}

// ======================= launch =======================
extern "C" void kernel_launch(void* const* d_in, const int* in_sizes, int n_in,
                              void* d_out, int out_size, void* d_ws, size_t ws_size,
                              hipStream_t stream) {
    const float* x  = (const float*)d_in[0];
    const float* wq = (const float*)d_in[1];
    const float* wk = (const float*)d_in[2];
    const float* wv = (const float*)d_in[3];
    const float* wo = (const float*)d_in[4];
    const float* q_scale = (const float*)d_in[5];
    const float* k_scale = (const float*)d_in[6];
    float* out = (float*)d_out;

    const size_t T = (size_t)BATCH * SEQ * NH * HD;   // 8388608
    const size_t W = (size_t)EMB * NH * HD;           // 4194304

    float* q = (float*)d_ws;                          // fp32 [b,s,h,d]
    float* k = q + T;
    float* v = k + T;
    unsigned short* xh   = (unsigned short*)(v + T);  // reused as Qh after GEMMs
    unsigned short* xl   = xh + T;                    // reused as Ql
    unsigned short* aob  = xl + T;
    unsigned short* Kh   = aob + T;
    unsigned short* Kl   = Kh + T;
    unsigned short* Vtb  = Kl + T;
    unsigned short* wqTh = Vtb + T;
    unsigned short* wqTl = wqTh + W;
    unsigned short* wkTh = wqTl + W;
    unsigned short* wkTl = wkTh + W;
    unsigned short* wvT  = wkTl + W;
    unsigned short* woT  = wvT + W;

    const int M = BATCH * SEQ;   // 4096
    const int N = NH * HD;       // 2048
    const int K = EMB;           // 2048

    cast_split_f32<<<(int)(T / 4 + 255) / 256, 256, 0, stream>>>(x, xh, xl, (int)T);
    dim3 tblk(32, 8);
    transpose_cast_split<<<dim3(N / 32, K / 32), tblk, 0, stream>>>(wq, wqTh, wqTl, K, N);
    transpose_cast_split<<<dim3(N / 32, K / 32), tblk, 0, stream>>>(wk, wkTh, wkTl, K, N);
    transpose_cast<<<dim3(N / 32, K / 32), tblk, 0, stream>>>(wv, wvT, K, N);
    transpose_cast<<<dim3(EMB / 32, (NH * HD) / 32), tblk, 0, stream>>>(wo, woT, NH * HD, EMB);

    dim3 ggrid(N / GT, M / GT);
    gemm_bf16_split<<<ggrid, 256, 0, stream>>>(xh, xl, wqTh, wqTl, q, M, N, K);
    gemm_bf16_split<<<ggrid, 256, 0, stream>>>(xh, xl, wkTh, wkTl, k, M, N, K);
    gemm_bf16<<<ggrid, 256, 0, stream>>>(xh, wvT, v, M, N, K);

    unsigned short* Qh = xh;
    unsigned short* Ql = xl;
    prep_qk<<<(int)(T / 128 / 2), 256, 0, stream>>>(q, q_scale, Qh, Ql, 0);
    prep_qk<<<(int)(T / 128 / 2), 256, 0, stream>>>(k, k_scale, Kh, Kl, 1);
    prep_v<<<dim3(SEQ / ATK, BATCH * NH), 256, 0, stream>>>(v, Vtb);

    attn7<<<dim3(SEQ / ATQ, BATCH * NH), 1024, 0, stream>>>(Qh, Ql, Kh, Kl, Vtb, (__hip_bfloat16*)aob);

    gemm_bf16<<<dim3(EMB / GT, M / GT), 256, 0, stream>>>(aob, woT, out, M, EMB, NH * HD);
}